// Round 6
// baseline (308.792 us; speedup 1.0000x reference)
//
#include <hip/hip_runtime.h>
#include <hip/hip_cooperative_groups.h>
#include <stdint.h>

namespace cg = cooperative_groups;

#define N_ANCH 33600
#define BS 16
#define NCH 56
#define MAX_NMS 3000
#define MAX_DET 300
#define CONF_T 0.25f
#define IOU_T 0.7f
#define IMG 1280.0f
#define NW 47                         // 47*64 = 3008 >= 3000 bits
#define NBINS 4096
#define HIST_BINS 4097
#define CAP 4096                      // candidate slots per image
#define WCAP 4096                     // worklist entries per image
#define WC_STRIDE 16
#define NIT 9                         // ceil((N_ANCH/4)/1024) conf float4s per thread
#define NBLK 256                      // cooperative grid size (1-2 blocks/CU guaranteed)

// ---- ws layout (bytes) ---- (everything written before read; no memset needed)
#define OFF_CAND 0                                        // 16*4096*8  = 524288
#define OFF_WL   (OFF_CAND + BS*CAP*8)                    // 16*4096*4  = 262144
#define OFF_META (OFF_WL + BS*WCAP*4)                     // 16*3000*8  = 384000
#define OFF_BOX  ((OFF_META + BS*MAX_NMS*8 + 15) & ~15)   // 16*3000*16 = 768000
#define OFF_WC   (OFF_BOX + BS*MAX_NMS*16)                // 16*16*4    = 1024
#define OFF_GBM  (OFF_WC + BS*WC_STRIDE*4)                // 16*8       = 128
#define OFF_FOI  (OFF_GBM + BS*8)                         // 16*300*4   = 19200

__device__ __forceinline__ int score_bucket(float c, uint32_t* bits_out) {
    if (!(c > CONF_T)) { *bits_out = 0u; return 0; }
    uint32_t bits = __float_as_uint(c);
    *bits_out = bits;
    int bucket = (int)(bits >> 12) - 0x3E800 + 1;
    bucket = bucket < 1 ? 1 : (bucket > NBINS ? NBINS : bucket);
    return bucket;
}

__device__ __forceinline__ float iou_pair(float4 bi, float ai, float4 bj) {
    float aj  = (bj.z - bj.x) * (bj.w - bj.y);
    float ltx = fmaxf(bi.x, bj.x), lty = fmaxf(bi.y, bj.y);
    float rbx = fminf(bi.z, bj.z), rby = fminf(bi.w, bj.w);
    float wx  = fmaxf(rbx - ltx, 0.f), wy = fmaxf(rby - lty, 0.f);
    float inter = wx * wy;
    return inter / (ai + aj - inter + 1e-9f);
}

__device__ __forceinline__ unsigned long long readlane64(unsigned long long v, int lane) {
    uint32_t lo = (uint32_t)v, hi = (uint32_t)(v >> 32);
    uint32_t rlo = __builtin_amdgcn_readlane(lo, lane);
    uint32_t rhi = __builtin_amdgcn_readlane(hi, lane);
    return ((unsigned long long)rhi << 32) | (unsigned long long)rlo;
}

// ---- Cooperative mega-kernel: P1 front-end | P2 rank | P3 NMS | P4 kpt ----
// 256 blocks x 1024 threads. LDS ~56.1 KB: lbox[3000] (48 KB, P3) aliases the
// hist/scan region (34.8 KB, P1) — layout proven correct in the R2 fused kernel.
__global__ void __launch_bounds__(1024)
k_mega(const float* __restrict__ preds,
       unsigned long long* __restrict__ cand,
       unsigned int* __restrict__ wlist, int* __restrict__ wcount,
       int2* __restrict__ gbm,
       uint2* __restrict__ meta, float4* __restrict__ box_ws,
       int* __restrict__ foi, float* __restrict__ out) {
    cg::grid_group grid = cg::this_grid();
    __shared__ __align__(16) char sraw[48000];
    __shared__ float4 kbox[MAX_DET];
    __shared__ float  karea[MAX_DET];
    __shared__ int    lsel[MAX_DET];
    __shared__ unsigned long long pres[NW];
    __shared__ unsigned long long diag[64];
    __shared__ unsigned long long keptmask_sh;
    __shared__ int ldsB, ldsM, ldsWc;
    const int blk = blockIdx.x, t = threadIdx.x;

    // ================= P1: per-image hist + scan + worklist + scatter (blocks 0..15) =================
    if (blk < BS) {
        const int b = blk;
        int* hl   = (int*)sraw;               // [4097]
        int* st   = (int*)(sraw + 16388);     // [4097]
        int* part = (int*)(sraw + 32776);     // [256]
        int* suf  = (int*)(sraw + 33800);     // [256]  (ends 34824 < 48000)
        if (t == 0) ldsWc = 0;
        for (int i = t; i < HIST_BINS; i += 1024) hl[i] = 0;
        __syncthreads();
        const float4* conf4 = (const float4*)(preds + (size_t)b * NCH * N_ANCH + 4 * N_ANCH);
        float4 rc[NIT];                       // register cache of this thread's conf values
        #pragma unroll
        for (int it = 0; it < NIT; it++) {
            int a4 = t + it * 1024;
            if (a4 < N_ANCH / 4) {
                float4 c4 = conf4[a4];
                rc[it] = c4;
                uint32_t bits;
                int bk;
                bk = score_bucket(c4.x, &bits); if (bk > 0) atomicAdd(&hl[bk], 1);
                bk = score_bucket(c4.y, &bits); if (bk > 0) atomicAdd(&hl[bk], 1);
                bk = score_bucket(c4.z, &bits); if (bk > 0) atomicAdd(&hl[bk], 1);
                bk = score_bucket(c4.w, &bits); if (bk > 0) atomicAdd(&hl[bk], 1);
            }
        }
        __syncthreads();
        if (t < 256) {
            int s = 0;
            for (int k = 0; k < 16; k++) s += hl[1 + t * 16 + k];
            part[t] = s;
        }
        __syncthreads();
        if (t == 0) {
            int run = 0;
            for (int i = 255; i >= 0; i--) { suf[i] = run; run += part[i]; }
            if (run < MAX_NMS) { ldsB = 1; ldsM = run; }   // fewer than 3000 valid
        }
        __syncthreads();
        if (t < 256) {
            int run = suf[t];
            bool maycross = (run < MAX_NMS) && (run + part[t] >= MAX_NMS);
            bool done = false;
            for (int k = 15; k >= 0; k--) {
                int bin = 1 + t * 16 + k;
                st[bin] = run;
                run += hl[bin];
                if (maycross && !done && run >= MAX_NMS) { ldsB = bin; ldsM = run; done = true; }
            }
        }
        __syncthreads();
        const int B = ldsB;
        // worklist of segments intersecting the top-3000 (reads st before cursors mutate)
        if (t < 256) {
            for (int k = 0; k < 16; k++) {
                int bin = 1 + t * 16 + k;
                int c = hl[bin], s = st[bin];
                if (c > 0 && bin >= B && s < MAX_NMS) {
                    int idx = atomicAdd(&ldsWc, 1);
                    wlist[b * WCAP + idx] = (unsigned int)s | ((unsigned int)c << 16);
                }
            }
        }
        __syncthreads();
        // scatter candidates from register cache (st doubles as cursor)
        #pragma unroll
        for (int it = 0; it < NIT; it++) {
            int a4 = t + it * 1024;
            if (a4 < N_ANCH / 4) {
                float4 c4 = rc[it];
                float cv[4] = {c4.x, c4.y, c4.z, c4.w};
                #pragma unroll
                for (int q = 0; q < 4; q++) {
                    uint32_t bits;
                    int bucket = score_bucket(cv[q], &bits);
                    if (bucket >= B && bucket > 0) {
                        int pos = atomicAdd(&st[bucket], 1);
                        if (pos < CAP) {
                            int a = a4 * 4 + q;
                            cand[b * CAP + pos] =
                                ((unsigned long long)bits << 32) | (uint32_t)(~(uint32_t)a);
                        }
                    }
                }
            }
        }
        if (t == 0) {
            wcount[b * WC_STRIDE] = ldsWc;
            gbm[b] = make_int2(ldsB, ldsM);
        }
    }
    grid.sync();

    // ================= P2: wide rank (all 256 blocks; 256 waves/image) =================
    {
        const int gw = blk * 16 + (t >> 6);   // global wave id 0..4095
        const int lane = t & 63;
        const int b = gw & 15;                // image
        const int wv = gw >> 4;               // 0..255 within image
        const int wc = wcount[b * WC_STRIDE];
        const float* pr = preds + (size_t)b * NCH * N_ANCH;
        for (int e = wv; e < wc; e += 256) {
            unsigned int ent = wlist[b * WCAP + e];
            int s = (int)(ent & 0xffffu);
            int n = (int)(ent >> 16);
            if (s + n > CAP) n = CAP - s;
            const unsigned long long* seg = cand + b * CAP + s;
            for (int i = lane; i < n; i += 64) {
                unsigned long long ke = seg[i];
                int r = 0;
                for (int j = 0; j < n; j++) r += (seg[j] > ke);
                int pos = s + r;
                if (pos < MAX_NMS) {
                    int oi = (int)(~(uint32_t)ke);
                    uint32_t sbits = (uint32_t)(ke >> 32);
                    float cx = pr[0 * N_ANCH + oi], cy = pr[1 * N_ANCH + oi];
                    float w  = pr[2 * N_ANCH + oi], h  = pr[3 * N_ANCH + oi];
                    float4 bx;
                    bx.x = fminf(fmaxf(cx - w * 0.5f, 0.f), IMG);
                    bx.y = fminf(fmaxf(cy - h * 0.5f, 0.f), IMG);
                    bx.z = fminf(fmaxf(cx + w * 0.5f, 0.f), IMG);
                    bx.w = fminf(fmaxf(cy + h * 0.5f, 0.f), IMG);
                    box_ws[b * MAX_NMS + pos] = bx;
                    meta[b * MAX_NMS + pos] = make_uint2((unsigned int)oi, sbits);
                }
            }
        }
    }
    grid.sync();

    // ================= P3: greedy NMS (blocks 0..15; lbox aliases dead hist region) =================
    if (blk < BS) {
        const int b = blk;
        float4* lbox = (float4*)sraw;         // [3000]
        const int M = gbm[b].y;
        const int Mc = M < MAX_NMS ? M : MAX_NMS;
        for (int j = t; j < Mc; j += 1024) lbox[j] = box_ws[b * MAX_NMS + j];
        if (t < NW) {
            int base = t * 64;
            int lo = Mc - base;
            unsigned long long inv = (lo <= 0) ? ~0ull : (lo >= 64 ? 0ull : ~((1ull << lo) - 1ull));
            pres[t] = inv;    // bit set = invalid/suppressed
        }
        __syncthreads();
        int kc = 0;
        const int nch = (Mc + 63) >> 6;
        for (int c = 0; c < nch && kc < MAX_DET; c++) {
            int base = c * 64;
            if (t < 64) diag[t] = 0ull;
            __syncthreads();
            {   // suppression of chunk boxes by already-kept boxes (pull)
                int jl = t >> 4, kk = t & 15;
                int j = base + jl;
                if (j < Mc && kc > 0) {
                    float4 bj = lbox[j];
                    bool sup = false;
                    for (int kidx = kk; kidx < kc; kidx += 16) {
                        if (iou_pair(kbox[kidx], karea[kidx], bj) > IOU_T) { sup = true; break; }
                    }
                    if (sup) atomicOr(&pres[c], 1ull << jl);
                }
            }
            {   // intra-chunk 64x64
                int il = t >> 4;
                int j0 = (t & 15) * 4;
                int i = base + il;
                if (i < Mc) {
                    float4 bi = lbox[i];
                    float ai = (bi.z - bi.x) * (bi.w - bi.y);
                    unsigned long long m = 0ull;
                    for (int q = 0; q < 4; q++) {
                        int jl = j0 + q, j = base + jl;
                        if (j > i && j < Mc) {
                            if (iou_pair(bi, ai, lbox[j]) > IOU_T) m |= 1ull << jl;
                        }
                    }
                    if (m) atomicOr(&diag[il], m);
                }
            }
            __syncthreads();
            if (t < 64) {   // greedy bit loop on wave 0, diag via readlane
                unsigned long long mydiag = diag[t];
                unsigned long long s = pres[c];
                unsigned long long keptm = 0ull;
                int room = MAX_DET - kc;
                int jmax = Mc - base; if (jmax > 64) jmax = 64;
                for (int bb = 0; bb < jmax; bb++) {
                    if (!((s >> bb) & 1ull)) {
                        s |= readlane64(mydiag, bb);
                        keptm |= 1ull << bb;
                        if (--room == 0) break;
                    }
                }
                if (t == 0) keptmask_sh = keptm;
            }
            __syncthreads();
            unsigned long long keptm = keptmask_sh;
            if (t < 64 && ((keptm >> t) & 1ull)) {
                int pos = kc + __popcll(keptm & ((1ull << t) - 1ull));
                float4 bx = lbox[base + t];
                kbox[pos] = bx;
                karea[pos] = (bx.z - bx.x) * (bx.w - bx.y);
                lsel[pos] = base + t;
            }
            kc += __popcll(keptm);
            __syncthreads();
        }
        // outputs: boxes (16,300,4), scores (16,300,1), final anchor idx for P4
        float* ob  = out;
        float* osc = out + BS * MAX_DET * 4;
        for (int r = t; r < MAX_DET; r += 1024) {
            int det = b * MAX_DET + r;
            if (r < kc) {
                float4 bx = kbox[r];
                ob[det * 4 + 0] = bx.x; ob[det * 4 + 1] = bx.y;
                ob[det * 4 + 2] = bx.z; ob[det * 4 + 3] = bx.w;
                uint2 mt = meta[b * MAX_NMS + lsel[r]];
                osc[det] = __uint_as_float(mt.y);
                foi[det] = (int)mt.x;
            } else {
                ob[det * 4 + 0] = 0.f; ob[det * 4 + 1] = 0.f;
                ob[det * 4 + 2] = 0.f; ob[det * 4 + 3] = 0.f;
                osc[det] = 0.f;
                foi[det] = -1;
            }
        }
    }
    grid.sync();

    // ================= P4: grid-wide keypoint gather (1 scattered load/thread) =================
    {
        const int g = blk * 1024 + t;              // 262144 threads >= 244800 elems
        if (g < BS * MAX_DET * 51) {
            int det = g / 51, lane = g - det * 51;
            int b = det / MAX_DET;
            float* okp = out + BS * MAX_DET * 5;   // (16,300,51)
            int oi = foi[det];
            float v = 0.f;
            if (oi >= 0) {
                v = preds[(size_t)b * NCH * N_ANCH + (size_t)(5 + lane) * N_ANCH + oi];
                if (lane < 2) v = fminf(fmaxf(v, 0.f), IMG); // ref clips only cols 0,1
            }
            okp[g] = v;
        }
    }
}

extern "C" void kernel_launch(void* const* d_in, const int* in_sizes, int n_in,
                              void* d_out, int out_size, void* d_ws, size_t ws_size,
                              hipStream_t stream) {
    const float* preds = (const float*)d_in[0];
    float* out = (float*)d_out;
    char* ws = (char*)d_ws;
    unsigned long long* cand = (unsigned long long*)(ws + OFF_CAND);
    unsigned int* wlist = (unsigned int*)(ws + OFF_WL);
    uint2* meta = (uint2*)(ws + OFF_META);
    float4* box = (float4*)(ws + OFF_BOX);
    int* wcount = (int*)(ws + OFF_WC);
    int2* gbm = (int2*)(ws + OFF_GBM);
    int* foi = (int*)(ws + OFF_FOI);

    void* args[] = {(void*)&preds, (void*)&cand, (void*)&wlist, (void*)&wcount,
                    (void*)&gbm, (void*)&meta, (void*)&box, (void*)&foi, (void*)&out};
    hipLaunchCooperativeKernel((const void*)k_mega, dim3(NBLK), dim3(1024),
                               args, 0, stream);
}

// Round 7
// 226.593 us; speedup vs baseline: 1.3628x; 1.3628x over previous
//
#include <hip/hip_runtime.h>
#include <stdint.h>

#define N_ANCH 33600
#define BS 16
#define NCH 56
#define MAX_NMS 3000
#define MAX_DET 300
#define CONF_T 0.25f
#define IOU_T 0.7f
#define IMG 1280.0f
#define NW 47                         // 47*64 = 3008 >= 3000 bits
#define NBINS 4096
#define HIST_BINS 4097
#define CAP 4096                      // candidate slots per image
#define WCAP 4096                     // worklist entries per image
#define WC_STRIDE 16
#define NIT 9                         // ceil((N_ANCH/4)/1024) conf float4s per thread

// ---- ws layout (bytes) ---- (everything written before read; no memset needed)
#define OFF_CAND 0                                        // 16*4096*8  = 524288
#define OFF_WL   (OFF_CAND + BS*CAP*8)                    // 16*4096*4  = 262144
#define OFF_META (OFF_WL + BS*WCAP*4)                     // 16*3000*8  = 384000
#define OFF_BOX  ((OFF_META + BS*MAX_NMS*8 + 15) & ~15)   // 16*3000*16 = 768000
#define OFF_WC   (OFF_BOX + BS*MAX_NMS*16)                // 16*16*4    = 1024
#define OFF_GBM  (OFF_WC + BS*WC_STRIDE*4)                // 16*8       = 128
#define OFF_FOI  (OFF_GBM + BS*8)                         // 16*300*4   = 19200

__device__ __forceinline__ int score_bucket(float c, uint32_t* bits_out) {
    if (!(c > CONF_T)) { *bits_out = 0u; return 0; }
    uint32_t bits = __float_as_uint(c);
    *bits_out = bits;
    int bucket = (int)(bits >> 12) - 0x3E800 + 1;
    bucket = bucket < 1 ? 1 : (bucket > NBINS ? NBINS : bucket);
    return bucket;
}

__device__ __forceinline__ float iou_pair(float4 bi, float ai, float4 bj) {
    float aj  = (bj.z - bj.x) * (bj.w - bj.y);
    float ltx = fmaxf(bi.x, bj.x), lty = fmaxf(bi.y, bj.y);
    float rbx = fminf(bi.z, bj.z), rby = fminf(bi.w, bj.w);
    float wx  = fmaxf(rbx - ltx, 0.f), wy = fmaxf(rby - lty, 0.f);
    float inter = wx * wy;
    return inter / (ai + aj - inter + 1e-9f);
}

__device__ __forceinline__ unsigned long long readlane64(unsigned long long v, int lane) {
    uint32_t lo = (uint32_t)v, hi = (uint32_t)(v >> 32);
    uint32_t rlo = __builtin_amdgcn_readlane(lo, lane);
    uint32_t rhi = __builtin_amdgcn_readlane(hi, lane);
    return ((unsigned long long)rhi << 32) | (unsigned long long)rlo;
}

// ---- K1: per-image hist + scan + worklist + scatter (reg conf-cache; parallel suffix scan) ----
__global__ void __launch_bounds__(1024)
k_phase1(const float* __restrict__ preds,
         unsigned long long* __restrict__ cand,
         unsigned int* __restrict__ wlist, int* __restrict__ wcount,
         int2* __restrict__ gbm) {
    __shared__ int hl[HIST_BINS];     // counts
    __shared__ int st[HIST_BINS];     // start offsets, later scatter cursors
    __shared__ int part[256];
    __shared__ int suf[256];
    __shared__ int ldsB, ldsM, ldsWc;
    const int b = blockIdx.x, t = threadIdx.x;    // 1024 threads
    if (t == 0) ldsWc = 0;
    for (int i = t; i < HIST_BINS; i += 1024) hl[i] = 0;
    __syncthreads();
    const float4* conf4 = (const float4*)(preds + (size_t)b * NCH * N_ANCH + 4 * N_ANCH);
    float4 rc[NIT];                   // register cache of this thread's conf values
    #pragma unroll
    for (int it = 0; it < NIT; it++) {
        int a4 = t + it * 1024;
        if (a4 < N_ANCH / 4) {
            float4 c4 = conf4[a4];
            rc[it] = c4;
            uint32_t bits;
            int bk;
            bk = score_bucket(c4.x, &bits); if (bk > 0) atomicAdd(&hl[bk], 1);
            bk = score_bucket(c4.y, &bits); if (bk > 0) atomicAdd(&hl[bk], 1);
            bk = score_bucket(c4.z, &bits); if (bk > 0) atomicAdd(&hl[bk], 1);
            bk = score_bucket(c4.w, &bits); if (bk > 0) atomicAdd(&hl[bk], 1);
        }
    }
    __syncthreads();
    if (t < 256) {
        int s = 0;
        for (int k = 0; k < 16; k++) s += hl[1 + t * 16 + k];
        part[t] = s;
    }
    __syncthreads();
    // wave-parallel suffix scan of part[256] on wave 0 (replaces 256-iter serial t==0 loop)
    if (t < 64) {
        int p0 = part[4 * t + 0], p1 = part[4 * t + 1];
        int p2 = part[4 * t + 2], p3 = part[4 * t + 3];
        int loc = p0 + p1 + p2 + p3;
        int v = loc;
        #pragma unroll
        for (int off = 1; off < 64; off <<= 1) {
            int src = t + off;
            int o = __shfl(v, src & 63);   // all lanes participate; masked add below
            if (src < 64) v += o;
        }
        int above = v - loc;               // sum over lanes > t
        suf[4 * t + 0] = above + p1 + p2 + p3;
        suf[4 * t + 1] = above + p2 + p3;
        suf[4 * t + 2] = above + p3;
        suf[4 * t + 3] = above;
        if (t == 0) {
            if (v < MAX_NMS) { ldsB = 1; ldsM = v; }   // fewer than 3000 valid total
        }
    }
    __syncthreads();
    if (t < 256) {
        int run = suf[t];
        bool maycross = (run < MAX_NMS) && (run + part[t] >= MAX_NMS);
        bool done = false;
        for (int k = 15; k >= 0; k--) {
            int bin = 1 + t * 16 + k;
            st[bin] = run;
            run += hl[bin];
            if (maycross && !done && run >= MAX_NMS) { ldsB = bin; ldsM = run; done = true; }
        }
    }
    __syncthreads();
    const int B = ldsB;
    // worklist of segments intersecting the top-3000 (reads st before cursors mutate)
    if (t < 256) {
        for (int k = 0; k < 16; k++) {
            int bin = 1 + t * 16 + k;
            int c = hl[bin], s = st[bin];
            if (c > 0 && bin >= B && s < MAX_NMS) {
                int idx = atomicAdd(&ldsWc, 1);
                wlist[b * WCAP + idx] = (unsigned int)s | ((unsigned int)c << 16);
            }
        }
    }
    __syncthreads();
    // scatter candidates from register cache (st doubles as cursor); no global re-read
    #pragma unroll
    for (int it = 0; it < NIT; it++) {
        int a4 = t + it * 1024;
        if (a4 < N_ANCH / 4) {
            float4 c4 = rc[it];
            float cv[4] = {c4.x, c4.y, c4.z, c4.w};
            #pragma unroll
            for (int q = 0; q < 4; q++) {
                uint32_t bits;
                int bucket = score_bucket(cv[q], &bits);
                if (bucket >= B && bucket > 0) {
                    int pos = atomicAdd(&st[bucket], 1);
                    if (pos < CAP) {
                        int a = a4 * 4 + q;
                        cand[b * CAP + pos] =
                            ((unsigned long long)bits << 32) | (uint32_t)(~(uint32_t)a);
                    }
                }
            }
        }
    }
    if (t == 0) {
        wcount[b * WC_STRIDE] = ldsWc;
        gbm[b] = make_int2(ldsB, ldsM);
    }
}

// ---- K2: wide rank within segments + clipped box + meta write (proven) ----
__global__ void k_rank(const float* __restrict__ preds,
                       const unsigned long long* __restrict__ cand,
                       const unsigned int* __restrict__ wlist,
                       const int* __restrict__ wcount,
                       uint2* __restrict__ meta, float4* __restrict__ box_ws) {
    const int b = blockIdx.x;
    const int wc = wcount[b * WC_STRIDE];
    const int wv = blockIdx.y * (blockDim.x >> 6) + (threadIdx.x >> 6);
    const int lane = threadIdx.x & 63;
    const int wstride = gridDim.y * (blockDim.x >> 6);
    const float* pr = preds + (size_t)b * NCH * N_ANCH;
    for (int e = wv; e < wc; e += wstride) {
        unsigned int ent = wlist[b * WCAP + e];
        int s = (int)(ent & 0xffffu);
        int n = (int)(ent >> 16);
        if (s + n > CAP) n = CAP - s;
        const unsigned long long* seg = cand + b * CAP + s;
        for (int i = lane; i < n; i += 64) {
            unsigned long long ke = seg[i];
            int r = 0;
            for (int j = 0; j < n; j++) r += (seg[j] > ke);
            int pos = s + r;
            if (pos < MAX_NMS) {
                int oi = (int)(~(uint32_t)ke);
                uint32_t sbits = (uint32_t)(ke >> 32);
                float cx = pr[0 * N_ANCH + oi], cy = pr[1 * N_ANCH + oi];
                float w  = pr[2 * N_ANCH + oi], h  = pr[3 * N_ANCH + oi];
                float4 bx;
                bx.x = fminf(fmaxf(cx - w * 0.5f, 0.f), IMG);
                bx.y = fminf(fmaxf(cy - h * 0.5f, 0.f), IMG);
                bx.z = fminf(fmaxf(cx + w * 0.5f, 0.f), IMG);
                bx.w = fminf(fmaxf(cy + h * 0.5f, 0.f), IMG);
                box_ws[b * MAX_NMS + pos] = bx;
                meta[b * MAX_NMS + pos] = make_uint2((unsigned int)oi, sbits);
            }
        }
    }
}

// ---- K3: greedy NMS on LDS boxes (16 blocks; Mc-guarded, no pad writes) ----
__global__ void __launch_bounds__(1024)
k_nms(const float4* __restrict__ box_ws, const uint2* __restrict__ meta,
      const int2* __restrict__ gbm, int* __restrict__ foi, float* __restrict__ out) {
    __shared__ float4 lbox[MAX_NMS];
    __shared__ float4 kbox[MAX_DET];
    __shared__ float  karea[MAX_DET];
    __shared__ int    lsel[MAX_DET];
    __shared__ unsigned long long pres[NW];
    __shared__ unsigned long long diag[64];
    __shared__ unsigned long long keptmask_sh;
    const int b = blockIdx.x, t = threadIdx.x;
    const int M = gbm[b].y;
    const int Mc = M < MAX_NMS ? M : MAX_NMS;
    for (int j = t; j < Mc; j += 1024) lbox[j] = box_ws[b * MAX_NMS + j];
    if (t < NW) {
        int base = t * 64;
        int lo = Mc - base;
        unsigned long long inv = (lo <= 0) ? ~0ull : (lo >= 64 ? 0ull : ~((1ull << lo) - 1ull));
        pres[t] = inv;    // bit set = invalid/suppressed
    }
    __syncthreads();
    int kc = 0;
    const int nch = (Mc + 63) >> 6;
    for (int c = 0; c < nch && kc < MAX_DET; c++) {
        int base = c * 64;
        if (t < 64) diag[t] = 0ull;
        __syncthreads();
        {   // suppression of chunk boxes by already-kept boxes (pull)
            int jl = t >> 4, kk = t & 15;
            int j = base + jl;
            if (j < Mc && kc > 0) {
                float4 bj = lbox[j];
                bool sup = false;
                for (int kidx = kk; kidx < kc; kidx += 16) {
                    if (iou_pair(kbox[kidx], karea[kidx], bj) > IOU_T) { sup = true; break; }
                }
                if (sup) atomicOr(&pres[c], 1ull << jl);
            }
        }
        {   // intra-chunk 64x64
            int il = t >> 4;
            int j0 = (t & 15) * 4;
            int i = base + il;
            if (i < Mc) {
                float4 bi = lbox[i];
                float ai = (bi.z - bi.x) * (bi.w - bi.y);
                unsigned long long m = 0ull;
                for (int q = 0; q < 4; q++) {
                    int jl = j0 + q, j = base + jl;
                    if (j > i && j < Mc) {
                        if (iou_pair(bi, ai, lbox[j]) > IOU_T) m |= 1ull << jl;
                    }
                }
                if (m) atomicOr(&diag[il], m);
            }
        }
        __syncthreads();
        if (t < 64) {   // greedy bit loop on wave 0, diag via readlane
            unsigned long long mydiag = diag[t];
            unsigned long long s = pres[c];
            unsigned long long keptm = 0ull;
            int room = MAX_DET - kc;
            int jmax = Mc - base; if (jmax > 64) jmax = 64;
            for (int bb = 0; bb < jmax; bb++) {
                if (!((s >> bb) & 1ull)) {
                    s |= readlane64(mydiag, bb);
                    keptm |= 1ull << bb;
                    if (--room == 0) break;
                }
            }
            if (t == 0) keptmask_sh = keptm;
        }
        __syncthreads();
        unsigned long long keptm = keptmask_sh;
        if (t < 64 && ((keptm >> t) & 1ull)) {
            int pos = kc + __popcll(keptm & ((1ull << t) - 1ull));
            float4 bx = lbox[base + t];
            kbox[pos] = bx;
            karea[pos] = (bx.z - bx.x) * (bx.w - bx.y);
            lsel[pos] = base + t;
        }
        kc += __popcll(keptm);
        __syncthreads();
    }
    // outputs: boxes (16,300,4), scores (16,300,1), final anchor idx for kpt gather
    float* ob  = out;
    float* osc = out + BS * MAX_DET * 4;
    for (int r = t; r < MAX_DET; r += 1024) {
        int det = b * MAX_DET + r;
        if (r < kc) {
            float4 bx = kbox[r];
            ob[det * 4 + 0] = bx.x; ob[det * 4 + 1] = bx.y;
            ob[det * 4 + 2] = bx.z; ob[det * 4 + 3] = bx.w;
            uint2 mt = meta[b * MAX_NMS + lsel[r]];
            osc[det] = __uint_as_float(mt.y);
            foi[det] = (int)mt.x;
        } else {
            ob[det * 4 + 0] = 0.f; ob[det * 4 + 1] = 0.f;
            ob[det * 4 + 2] = 0.f; ob[det * 4 + 3] = 0.f;
            osc[det] = 0.f;
            foi[det] = -1;
        }
    }
}

// ---- K4: wide keypoint gather (2-deep dependent chain: foi -> preds; full-GPU TLP) ----
__global__ void k_kpt(const float* __restrict__ preds, const int* __restrict__ foi,
                      float* __restrict__ out) {
    int g = blockIdx.x * blockDim.x + threadIdx.x;   // 16*300*64 threads
    int det = g >> 6, lane = g & 63;
    if (det >= BS * MAX_DET || lane >= 51) return;
    int b = det / MAX_DET;
    float* okp = out + BS * MAX_DET * 5;             // (16,300,51)
    int oi = foi[det];
    if (oi >= 0) {
        float v = preds[(size_t)b * NCH * N_ANCH + (size_t)(5 + lane) * N_ANCH + oi];
        if (lane < 2) v = fminf(fmaxf(v, 0.f), IMG); // ref clips only cols 0,1
        okp[det * 51 + lane] = v;
    } else {
        okp[det * 51 + lane] = 0.f;
    }
}

extern "C" void kernel_launch(void* const* d_in, const int* in_sizes, int n_in,
                              void* d_out, int out_size, void* d_ws, size_t ws_size,
                              hipStream_t stream) {
    const float* preds = (const float*)d_in[0];
    float* out = (float*)d_out;
    char* ws = (char*)d_ws;
    unsigned long long* cand = (unsigned long long*)(ws + OFF_CAND);
    unsigned int* wlist = (unsigned int*)(ws + OFF_WL);
    uint2* meta = (uint2*)(ws + OFF_META);
    float4* box = (float4*)(ws + OFF_BOX);
    int* wcount = (int*)(ws + OFF_WC);
    int2* gbm = (int2*)(ws + OFF_GBM);
    int* foi = (int*)(ws + OFF_FOI);

    k_phase1<<<BS, 1024, 0, stream>>>(preds, cand, wlist, wcount, gbm);
    k_rank<<<dim3(BS, 32), 256, 0, stream>>>(preds, cand, wlist, wcount, meta, box);
    k_nms<<<BS, 1024, 0, stream>>>(box, meta, gbm, foi, out);
    k_kpt<<<(BS * MAX_DET * 64 + 255) / 256, 256, 0, stream>>>(preds, foi, out);
}